// Round 2
// baseline (97.117 us; speedup 1.0000x reference)
//
#include <hip/hip_runtime.h>
#include <math.h>

namespace {
constexpr int Bn = 8192, Pn = 128, Dn = 128;
constexpr int BT = 32, PT = 64, KC = 32;          // block tile: 32 b-rows x 64 p-rows, K-chunk 32
constexpr int NCHUNK = Dn / KC;                   // 4
constexpr float MAXN = 1.0f - 1e-5f;              // (1-PROJ_EPS)/sqrt(c)
constexpr float CLAMPV = 16.63553233343869f;      // log(2/eps32)
constexpr float SMOOTH = 50.0f;
}

// ---------------- per-p prep: projected bias, cx, bw, 1/a_norm, lambda_p*a_norm
__global__ void prep_p_kernel(const float* __restrict__ weight,
                              const float* __restrict__ bias,
                              float* __restrict__ bp,
                              float* __restrict__ pp) {
  const int p = blockIdx.x;
  const int lane = threadIdx.x;  // 0..63
  const float* br = bias + p * Dn;
  const float* wr = weight + p * Dn;
  float b0 = br[lane], b1 = br[lane + 64];
  float w0 = wr[lane], w1 = wr[lane + 64];
  double nb2 = (double)b0 * b0 + (double)b1 * b1;
#pragma unroll
  for (int off = 32; off; off >>= 1) nb2 += __shfl_xor(nb2, off);
  double norm = sqrt(nb2);
  if (norm < 1e-15) norm = 1e-15;
  double scl = (norm > (double)MAXN) ? (double)MAXN / norm : 1.0;
  float bp0 = (float)((double)b0 * scl);
  float bp1 = (float)((double)b1 * scl);
  bp[p * Dn + lane] = bp0;
  bp[p * Dn + lane + 64] = bp1;
  double p2 = nb2 * scl * scl;
  double cx = 1.0 - p2;                 // = coef_x = 1 - c*||p||^2
  double bwl = (double)bp0 * w0 + (double)bp1 * w1;
  double w2l = (double)w0 * w0 + (double)w1 * w1;
#pragma unroll
  for (int off = 32; off; off >>= 1) {
    bwl += __shfl_xor(bwl, off);
    w2l += __shfl_xor(w2l, off);
  }
  if (lane == 0) {
    double an = cx * sqrt(w2l);         // ||a|| = (1-p2)*||w||
    if (an < 1e-15) an = 1e-15;
    pp[p]          = (float)cx;
    pp[Pn + p]     = (float)bwl;        // <bias_proj, w>
    pp[2 * Pn + p] = (float)(1.0 / an);
    pp[3 * Pn + p] = (float)(2.0 / cx * an);  // lambda_p * a_norm
  }
}

// ---------------- per-b prep: x2 and 2/(1-x2), f64-accurate
__global__ void prep_x_kernel(const float* __restrict__ x, float* __restrict__ xb) {
  const int row = blockIdx.x * 4 + (threadIdx.x >> 6);
  const int lane = threadIdx.x & 63;
  const float* xr = x + row * Dn;
  float x0 = xr[lane], x1 = xr[lane + 64];
  double s = (double)x0 * x0 + (double)x1 * x1;
#pragma unroll
  for (int off = 32; off; off >>= 1) s += __shfl_xor(s, off);
  if (lane == 0) {
    xb[row] = (float)s;
    xb[Bn + row] = (float)(2.0 / (1.0 - s));
  }
}

// ---------------- main: dual-dot register-tiled GEMM + fused transcendental epilogue
// 512 blocks (2/CU, 8 waves/CU), 256 threads, micro-tile 2(b) x 4(p),
// LDS transposed [k][row] for vectorized ds_read, double-buffered async staging.
__global__ __launch_bounds__(256, 2)
void main_kernel(const float* __restrict__ x,
                 const float* __restrict__ weight,
                 const float* __restrict__ bp,
                 const float* __restrict__ pp,
                 const float* __restrict__ xb,
                 float* __restrict__ out) {
  __shared__ float xs[2][KC][BT + 2];   // pad 34: keeps float2 reads 8B-aligned
  __shared__ float wsh[2][KC][PT + 4];  // pad 68: keeps float4 reads 16B-aligned
  __shared__ float bsh[2][KC][PT + 4];

  const int tid = threadIdx.x;
  const int tx = tid & 15;              // p-direction (micro 4)
  const int ty = tid >> 4;              // b-direction (micro 2)
  const int b0 = blockIdx.x * BT;
  const int p0 = blockIdx.y * PT;

  // staging coords: coalesced global reads (8 lanes span one 128B row-chunk)
  const int xrow = tid >> 3;            // 0..31
  const int kq  = (tid & 7) * 4;        // 0,4,...,28
  const int wrow0 = tid >> 3;           // 0..31  (rep 0)
  const int wrow1 = (tid >> 3) + 32;    // 32..63 (rep 1)

  // ---- prologue: stage chunk 0 into buffer 0
  {
    float4 xv = *reinterpret_cast<const float4*>(x + (size_t)(b0 + xrow) * Dn + kq);
    float4 w0v = *reinterpret_cast<const float4*>(weight + (size_t)(p0 + wrow0) * Dn + kq);
    float4 w1v = *reinterpret_cast<const float4*>(weight + (size_t)(p0 + wrow1) * Dn + kq);
    float4 b0v = *reinterpret_cast<const float4*>(bp + (size_t)(p0 + wrow0) * Dn + kq);
    float4 b1v = *reinterpret_cast<const float4*>(bp + (size_t)(p0 + wrow1) * Dn + kq);
    xs[0][kq + 0][xrow] = xv.x; xs[0][kq + 1][xrow] = xv.y;
    xs[0][kq + 2][xrow] = xv.z; xs[0][kq + 3][xrow] = xv.w;
    wsh[0][kq + 0][wrow0] = w0v.x; wsh[0][kq + 1][wrow0] = w0v.y;
    wsh[0][kq + 2][wrow0] = w0v.z; wsh[0][kq + 3][wrow0] = w0v.w;
    wsh[0][kq + 0][wrow1] = w1v.x; wsh[0][kq + 1][wrow1] = w1v.y;
    wsh[0][kq + 2][wrow1] = w1v.z; wsh[0][kq + 3][wrow1] = w1v.w;
    bsh[0][kq + 0][wrow0] = b0v.x; bsh[0][kq + 1][wrow0] = b0v.y;
    bsh[0][kq + 2][wrow0] = b0v.z; bsh[0][kq + 3][wrow0] = b0v.w;
    bsh[0][kq + 0][wrow1] = b1v.x; bsh[0][kq + 1][wrow1] = b1v.y;
    bsh[0][kq + 2][wrow1] = b1v.z; bsh[0][kq + 3][wrow1] = b1v.w;
  }
  __syncthreads();

  float accw[2][4] = {};
  float accb[2][4] = {};
  int buf = 0;

  for (int c = 0; c < NCHUNK; ++c) {
    // T14 async-stage: issue next chunk's global loads BEFORE compute,
    // write to the other LDS buffer AFTER compute, one barrier per chunk.
    float4 nxv, nw0, nw1, nb0, nb1;
    const bool more = (c + 1 < NCHUNK);
    if (more) {
      const int k0 = (c + 1) * KC;
      nxv = *reinterpret_cast<const float4*>(x + (size_t)(b0 + xrow) * Dn + k0 + kq);
      nw0 = *reinterpret_cast<const float4*>(weight + (size_t)(p0 + wrow0) * Dn + k0 + kq);
      nw1 = *reinterpret_cast<const float4*>(weight + (size_t)(p0 + wrow1) * Dn + k0 + kq);
      nb0 = *reinterpret_cast<const float4*>(bp + (size_t)(p0 + wrow0) * Dn + k0 + kq);
      nb1 = *reinterpret_cast<const float4*>(bp + (size_t)(p0 + wrow1) * Dn + k0 + kq);
    }
#pragma unroll
    for (int k = 0; k < KC; ++k) {
      float2 xv = *reinterpret_cast<const float2*>(&xs[buf][k][ty * 2]);
      float4 wv = *reinterpret_cast<const float4*>(&wsh[buf][k][tx * 4]);
      float4 bv = *reinterpret_cast<const float4*>(&bsh[buf][k][tx * 4]);
      float xa[2] = {xv.x, xv.y};
      float wa[4] = {wv.x, wv.y, wv.z, wv.w};
      float ba[4] = {bv.x, bv.y, bv.z, bv.w};
#pragma unroll
      for (int i = 0; i < 2; ++i)
#pragma unroll
        for (int j = 0; j < 4; ++j) {
          accw[i][j] = fmaf(xa[i], wa[j], accw[i][j]);
          accb[i][j] = fmaf(xa[i], ba[j], accb[i][j]);
        }
    }
    if (more) {
      const int nb = buf ^ 1;
      xs[nb][kq + 0][xrow] = nxv.x; xs[nb][kq + 1][xrow] = nxv.y;
      xs[nb][kq + 2][xrow] = nxv.z; xs[nb][kq + 3][xrow] = nxv.w;
      wsh[nb][kq + 0][wrow0] = nw0.x; wsh[nb][kq + 1][wrow0] = nw0.y;
      wsh[nb][kq + 2][wrow0] = nw0.z; wsh[nb][kq + 3][wrow0] = nw0.w;
      wsh[nb][kq + 0][wrow1] = nw1.x; wsh[nb][kq + 1][wrow1] = nw1.y;
      wsh[nb][kq + 2][wrow1] = nw1.z; wsh[nb][kq + 3][wrow1] = nw1.w;
      bsh[nb][kq + 0][wrow0] = nb0.x; bsh[nb][kq + 1][wrow0] = nb0.y;
      bsh[nb][kq + 2][wrow0] = nb0.z; bsh[nb][kq + 3][wrow0] = nb0.w;
      bsh[nb][kq + 0][wrow1] = nb1.x; bsh[nb][kq + 1][wrow1] = nb1.y;
      bsh[nb][kq + 2][wrow1] = nb1.z; bsh[nb][kq + 3][wrow1] = nb1.w;
    }
    __syncthreads();
    buf ^= 1;
  }

  // ---- epilogue: per-(b,p) scalar math (den cancels analytically)
  float cxj[4], bwj[4], iaj[4], soj[4], x2i[2], fbi[2];
#pragma unroll
  for (int j = 0; j < 4; ++j) {
    int p = p0 + tx * 4 + j;
    cxj[j] = pp[p]; bwj[j] = pp[Pn + p]; iaj[j] = pp[2 * Pn + p]; soj[j] = pp[3 * Pn + p];
  }
#pragma unroll
  for (int i = 0; i < 2; ++i) {
    int b = b0 + ty * 2 + i;
    x2i[i] = xb[b]; fbi[i] = xb[Bn + b];
  }

#pragma unroll
  for (int i = 0; i < 2; ++i) {
    int b = b0 + ty * 2 + i;
    float res[4];
#pragma unroll
    for (int j = 0; j < 4; ++j) {
      float sb = accb[i][j];                     // <bias_proj, x>
      float xw = accw[i][j];                     // <w, x>
      float coefp = 1.0f + x2i[i] - 2.0f * sb;   // 1 + 2c*dot + c*x2
      float X = cxj[j] * xw - coefp * bwj[j];
      float arg = X * fbi[i] * iaj[j];           // den cancels
      // smooth_clamp(arg, -C, C, 50) with stable softplus
      float z1 = SMOOTH * (arg + CLAMPV);
      float z2 = SMOOTH * (arg - CLAMPV);
      float sp1 = fmaxf(z1, 0.0f) + log1pf(expf(-fabsf(z1)));
      float sp2 = fmaxf(z2, 0.0f) + log1pf(expf(-fabsf(z2)));
      float argc = -CLAMPV + (sp1 - sp2) * (1.0f / SMOOTH);
      res[j] = soj[j] * asinhf(argc);
    }
    *reinterpret_cast<float4*>(out + (size_t)b * Pn + p0 + tx * 4) =
        make_float4(res[0], res[1], res[2], res[3]);
  }
}

extern "C" void kernel_launch(void* const* d_in, const int* in_sizes, int n_in,
                              void* d_out, int out_size, void* d_ws, size_t ws_size,
                              hipStream_t stream) {
  const float* x = (const float*)d_in[0];
  const float* w = (const float*)d_in[1];
  const float* bias = (const float*)d_in[2];
  float* out = (float*)d_out;
  float* ws = (float*)d_ws;
  float* bpd = ws;                // [P][D] projected bias
  float* pp = bpd + Pn * Dn;      // 4*P per-p params
  float* xb = pp + 4 * Pn;        // 2*B per-b params

  hipLaunchKernelGGL(prep_p_kernel, dim3(Pn), dim3(64), 0, stream, w, bias, bpd, pp);
  hipLaunchKernelGGL(prep_x_kernel, dim3(Bn / 4), dim3(256), 0, stream, x, xb);
  hipLaunchKernelGGL(main_kernel, dim3(Bn / BT, Pn / PT), dim3(256), 0, stream,
                     x, w, bpd, pp, xb, out);
}

// Round 3
// 39.075 us; speedup vs baseline: 2.4854x; 2.4854x over previous
//
#include <hip/hip_runtime.h>
#include <math.h>

namespace {
constexpr int Bn = 8192, Pn = 128, Dn = 128;
constexpr int BT = 64, PT = 32;                   // block tile: 64 b-rows x 32 p-rows
constexpr float MAXN = 1.0f - 1e-5f;              // (1-PROJ_EPS)/sqrt(c)
constexpr float CLAMPV = 16.63553233343869f;      // log(2/eps32)
constexpr float SMOOTH = 50.0f;
}

// ---------------- per-p prep: projected bias, cx, bw, 1/a_norm, lambda_p*a_norm
__global__ void prep_p_kernel(const float* __restrict__ weight,
                              const float* __restrict__ bias,
                              float* __restrict__ bp,
                              float* __restrict__ pp) {
  const int p = blockIdx.x;
  const int lane = threadIdx.x;  // 0..63
  const float* br = bias + p * Dn;
  const float* wr = weight + p * Dn;
  float b0 = br[lane], b1 = br[lane + 64];
  float w0 = wr[lane], w1 = wr[lane + 64];
  double nb2 = (double)b0 * b0 + (double)b1 * b1;
#pragma unroll
  for (int off = 32; off; off >>= 1) nb2 += __shfl_xor(nb2, off);
  double norm = sqrt(nb2);
  if (norm < 1e-15) norm = 1e-15;
  double scl = (norm > (double)MAXN) ? (double)MAXN / norm : 1.0;
  float bp0 = (float)((double)b0 * scl);
  float bp1 = (float)((double)b1 * scl);
  bp[p * Dn + lane] = bp0;
  bp[p * Dn + lane + 64] = bp1;
  double p2 = nb2 * scl * scl;
  double cx = 1.0 - p2;                 // = coef_x = 1 - c*||p||^2
  double bwl = (double)bp0 * w0 + (double)bp1 * w1;
  double w2l = (double)w0 * w0 + (double)w1 * w1;
#pragma unroll
  for (int off = 32; off; off >>= 1) {
    bwl += __shfl_xor(bwl, off);
    w2l += __shfl_xor(w2l, off);
  }
  if (lane == 0) {
    double an = cx * sqrt(w2l);         // ||a|| = (1-p2)*||w||
    if (an < 1e-15) an = 1e-15;
    pp[p]          = (float)cx;
    pp[Pn + p]     = (float)bwl;        // <bias_proj, w>
    pp[2 * Pn + p] = (float)(1.0 / an);
    pp[3 * Pn + p] = (float)(2.0 / cx * an);  // lambda_p * a_norm
  }
}

// ---------------- per-b prep: x2 and 2/(1-x2), f64-accurate (required: 1-x2 ~ 2e-5)
__global__ void prep_x_kernel(const float* __restrict__ x, float* __restrict__ xb) {
  const int row = blockIdx.x * 4 + (threadIdx.x >> 6);
  const int lane = threadIdx.x & 63;
  const float* xr = x + row * Dn;
  float x0 = xr[lane], x1 = xr[lane + 64];
  double s = (double)x0 * x0 + (double)x1 * x1;
#pragma unroll
  for (int off = 32; off; off >>= 1) s += __shfl_xor(s, off);
  if (lane == 0) {
    xb[row] = (float)s;
    xb[Bn + row] = (float)(2.0 / (1.0 - s));
  }
}

// ---------------- main: stage-once LDS (x,w swizzled), bp from global (L1/L2),
// micro-tile 4(b) x 2(p), ONE barrier, zero-barrier K-stream, fused epilogue.
__global__ __launch_bounds__(256, 3)
void main_kernel(const float* __restrict__ x,
                 const float* __restrict__ weight,
                 const float* __restrict__ bpg,
                 const float* __restrict__ pp,
                 const float* __restrict__ xb,
                 float* __restrict__ out) {
  __shared__ float4 xt4[BT * 32];   // 64 rows x 32 float4, XOR-swizzled cols
  __shared__ float4 wt4[PT * 32];   // 32 rows x 32 float4, XOR-swizzled cols

  const int tid = threadIdx.x;
  const int tx = tid & 15;          // p-direction (micro 2)
  const int ty = tid >> 4;          // b-direction (micro 4)
  const int b0 = blockIdx.x * BT;
  const int p0 = blockIdx.y * PT;

  // ---- stage x-tile (2048 slots) and w-tile (1024 slots), swizzle on LDS write.
  // Global read linear & coalesced; slot(r,c) = r*32 + (c ^ ((r>>2)&7)).
#pragma unroll
  for (int t = 0; t < 8; ++t) {
    int F = t * 256 + tid;
    int r = F >> 5, c = F & 31;
    float4 v = *reinterpret_cast<const float4*>(x + (size_t)(b0 + r) * Dn + c * 4);
    xt4[r * 32 + (c ^ ((r >> 2) & 7))] = v;
  }
#pragma unroll
  for (int t = 0; t < 4; ++t) {
    int F = t * 256 + tid;
    int r = F >> 5, c = F & 31;
    float4 v = *reinterpret_cast<const float4*>(weight + (size_t)(p0 + r) * Dn + c * 4);
    wt4[r * 32 + (c ^ ((r >> 2) & 7))] = v;
  }
  __syncthreads();

  float accw[4][2] = {};
  float accb[4][2] = {};
  const float4* bprow0 = reinterpret_cast<const float4*>(bpg + (size_t)(p0 + 2 * tx) * Dn);
  const float4* bprow1 = reinterpret_cast<const float4*>(bpg + (size_t)(p0 + 2 * tx + 1) * Dn);
  const int sx = ty & 7;        // (4ty+i)>>2 == ty for i<4
  const int sw = tx >> 1;       // (2tx+j)>>2 == tx>>1 for j<2
  const int xbase0 = (4 * ty + 0) * 32, xbase1 = (4 * ty + 1) * 32;
  const int xbase2 = (4 * ty + 2) * 32, xbase3 = (4 * ty + 3) * 32;
  const int wbase0 = (2 * tx + 0) * 32, wbase1 = (2 * tx + 1) * 32;

#pragma unroll 4
  for (int kb = 0; kb < 32; ++kb) {
    const int kx = kb ^ sx;
    const int kw = kb ^ sw;
    float4 xf[4], wf[2], bf[2];
    xf[0] = xt4[xbase0 + kx]; xf[1] = xt4[xbase1 + kx];
    xf[2] = xt4[xbase2 + kx]; xf[3] = xt4[xbase3 + kx];
    wf[0] = wt4[wbase0 + kw]; wf[1] = wt4[wbase1 + kw];
    bf[0] = bprow0[kb];       bf[1] = bprow1[kb];
#pragma unroll
    for (int i = 0; i < 4; ++i) {
#pragma unroll
      for (int j = 0; j < 2; ++j) {
        accw[i][j] = fmaf(xf[i].x, wf[j].x, accw[i][j]);
        accw[i][j] = fmaf(xf[i].y, wf[j].y, accw[i][j]);
        accw[i][j] = fmaf(xf[i].z, wf[j].z, accw[i][j]);
        accw[i][j] = fmaf(xf[i].w, wf[j].w, accw[i][j]);
        accb[i][j] = fmaf(xf[i].x, bf[j].x, accb[i][j]);
        accb[i][j] = fmaf(xf[i].y, bf[j].y, accb[i][j]);
        accb[i][j] = fmaf(xf[i].z, bf[j].z, accb[i][j]);
        accb[i][j] = fmaf(xf[i].w, bf[j].w, accb[i][j]);
      }
    }
  }

  // ---- epilogue: per-(b,p) scalar math (Mobius denominator cancels analytically)
  float cxj[2], bwj[2], iaj[2], soj[2], x2i[4], fbi[4];
#pragma unroll
  for (int j = 0; j < 2; ++j) {
    int p = p0 + 2 * tx + j;
    cxj[j] = pp[p]; bwj[j] = pp[Pn + p]; iaj[j] = pp[2 * Pn + p]; soj[j] = pp[3 * Pn + p];
  }
#pragma unroll
  for (int i = 0; i < 4; ++i) {
    int b = b0 + 4 * ty + i;
    x2i[i] = xb[b]; fbi[i] = xb[Bn + b];
  }

#pragma unroll
  for (int i = 0; i < 4; ++i) {
    int b = b0 + 4 * ty + i;
    float res[2];
#pragma unroll
    for (int j = 0; j < 2; ++j) {
      float sb = accb[i][j];                     // <bias_proj, x>
      float xw = accw[i][j];                     // <w, x>
      float coefp = 1.0f + x2i[i] - 2.0f * sb;   // 1 + 2c*dot + c*x2
      float X = cxj[j] * xw - coefp * bwj[j];
      float arg = X * fbi[i] * iaj[j];           // den cancels
      // smooth_clamp(arg, -C, C, 50) with stable softplus
      float z1 = SMOOTH * (arg + CLAMPV);
      float z2 = SMOOTH * (arg - CLAMPV);
      float sp1 = fmaxf(z1, 0.0f) + log1pf(expf(-fabsf(z1)));
      float sp2 = fmaxf(z2, 0.0f) + log1pf(expf(-fabsf(z2)));
      float argc = -CLAMPV + (sp1 - sp2) * (1.0f / SMOOTH);
      res[j] = soj[j] * asinhf(argc);
    }
    *reinterpret_cast<float2*>(out + (size_t)b * Pn + p0 + 2 * tx) =
        make_float2(res[0], res[1]);
  }
}

extern "C" void kernel_launch(void* const* d_in, const int* in_sizes, int n_in,
                              void* d_out, int out_size, void* d_ws, size_t ws_size,
                              hipStream_t stream) {
  const float* x = (const float*)d_in[0];
  const float* w = (const float*)d_in[1];
  const float* bias = (const float*)d_in[2];
  float* out = (float*)d_out;
  float* ws = (float*)d_ws;
  float* bpd = ws;                // [P][D] projected bias
  float* pp = bpd + Pn * Dn;      // 4*P per-p params
  float* xb = pp + 4 * Pn;        // 2*B per-b params

  hipLaunchKernelGGL(prep_p_kernel, dim3(Pn), dim3(64), 0, stream, w, bias, bpd, pp);
  hipLaunchKernelGGL(prep_x_kernel, dim3(Bn / 4), dim3(256), 0, stream, x, xb);
  hipLaunchKernelGGL(main_kernel, dim3(Bn / BT, Pn / PT), dim3(256), 0, stream,
                     x, w, bpd, pp, xb, out);
}